// Round 17
// baseline (334.082 us; speedup 1.0000x reference)
//
#include <hip/hip_runtime.h>
#include <hip/hip_fp16.h>

#define NN 50000
#define NE 800000
#define ETOT (NE + NN)
#define GG 1000
#define DD 96
#define HEADS 4
#define DHH 24
#define NL 3
#define SCAN_NB 49     // ceil(NN / 1024)
#define NB 256         // dst buckets (dst>>8): 196 used
#define EPB 2048       // edges per partition block (R16: 4096 -> 0.77 waves/SIMD)
#define EPT (EPB / 256)                    // 8 edges per thread
#define PART_NBLK ((NE + EPB - 1) / EPB)   // 391
#define GROWS 128      // gemm rows per block (R14/R16-proven)
#define RS4 25         // A-tile row stride in float4 (100 floats; 100%32=4 banks)

// ---------------- bucket partition of edges by dst>>8 ----------------
__global__ __launch_bounds__(256) void bucket_count(const int* __restrict__ ei,
                                                    int* __restrict__ gsize) {
    __shared__ int lh[NB];
    int t = threadIdx.x;
    lh[t] = 0;
    __syncthreads();
    int base = blockIdx.x * EPB + t * EPT;
    for (int k = 0; k < EPT; k += 4) {
        int j = base + k;
        if (j + 3 < NE) {
            int4 d = *(const int4*)(ei + NE + j);
            atomicAdd(&lh[d.x >> 8], 1);
            atomicAdd(&lh[d.y >> 8], 1);
            atomicAdd(&lh[d.z >> 8], 1);
            atomicAdd(&lh[d.w >> 8], 1);
        } else {
            for (int q = 0; q < 4 && j + q < NE; q++)
                atomicAdd(&lh[ei[NE + j + q] >> 8], 1);
        }
    }
    __syncthreads();
    if (lh[t]) atomicAdd(&gsize[t], lh[t]);
}

__global__ __launch_bounds__(256) void bucket_scan(const int* __restrict__ gsize,
                                                   int* __restrict__ cursor) {
    __shared__ int ts[NB];
    int t = threadIdx.x;
    int v = gsize[t];
    ts[t] = v;
    __syncthreads();
#pragma unroll
    for (int off = 1; off < NB; off <<= 1) {
        int add = (t >= off) ? ts[t - off] : 0;
        __syncthreads();
        ts[t] += add;
        __syncthreads();
    }
    cursor[t] = ts[t] - v;   // exclusive
}

// R15 lesson: deg atomics do NOT belong here (original edge order = random
// scatter, +15us). count_deg2 runs over the PARTITIONED array instead.
__global__ __launch_bounds__(256) void bucket_partition(const int* __restrict__ ei,
                                                        int* __restrict__ cursor,
                                                        int2* __restrict__ epart) {
    __shared__ int lh[NB], lbase[NB];
    int t = threadIdx.x;
    lh[t] = 0;
    __syncthreads();
    int base = blockIdx.x * EPB + t * EPT;
    for (int k = 0; k < EPT; k += 4) {      // pass 1: block histogram
        int j = base + k;
        if (j + 3 < NE) {
            int4 d = *(const int4*)(ei + NE + j);
            atomicAdd(&lh[d.x >> 8], 1);
            atomicAdd(&lh[d.y >> 8], 1);
            atomicAdd(&lh[d.z >> 8], 1);
            atomicAdd(&lh[d.w >> 8], 1);
        } else {
            for (int q = 0; q < 4 && j + q < NE; q++)
                atomicAdd(&lh[ei[NE + j + q] >> 8], 1);
        }
    }
    __syncthreads();
    int cnt = lh[t];
    if (cnt) lbase[t] = atomicAdd(&cursor[t], cnt);  // reserve contiguous range
    lh[t] = 0;                                       // reuse as rank counter
    __syncthreads();
    for (int k = 0; k < EPT; k += 4) {      // pass 2: grouped writes
        int j = base + k;
        if (j + 3 < NE) {
            int4 s = *(const int4*)(ei + j);
            int4 d = *(const int4*)(ei + NE + j);
            int b0 = d.x >> 8, b1 = d.y >> 8, b2 = d.z >> 8, b3 = d.w >> 8;
            int r0 = atomicAdd(&lh[b0], 1);
            int r1 = atomicAdd(&lh[b1], 1);
            int r2 = atomicAdd(&lh[b2], 1);
            int r3 = atomicAdd(&lh[b3], 1);
            epart[lbase[b0] + r0] = make_int2(d.x, s.x);
            epart[lbase[b1] + r1] = make_int2(d.y, s.y);
            epart[lbase[b2] + r2] = make_int2(d.z, s.z);
            epart[lbase[b3] + r3] = make_int2(d.w, s.w);
        } else {
            for (int q = 0; q < 4 && j + q < NE; q++) {
                int dd = ei[NE + j + q], ss = ei[j + q];
                int b = dd >> 8;
                int r = atomicAdd(&lh[b], 1);
                epart[lbase[b] + r] = make_int2(dd, ss);
            }
        }
    }
}

// ---------------- degree count on partitioned edges (localized atomics) ----------------
__global__ void count_deg2(const int2* __restrict__ epart, int* __restrict__ deg) {
    int j = (blockIdx.x * blockDim.x + threadIdx.x) * 4;
    if (j + 3 < NE) {
        int4 a = *(const int4*)(epart + j);       // (d,s,d,s)
        int4 b = *(const int4*)(epart + j + 2);
        atomicAdd(&deg[a.x], 1);
        atomicAdd(&deg[a.z], 1);
        atomicAdd(&deg[b.x], 1);
        atomicAdd(&deg[b.z], 1);
    } else {
        for (int k = 0; k < 4 && j + k < NE; k++) atomicAdd(&deg[epart[j + k].x], 1);
    }
}

// hierarchical scan, phase 1: deg[i]+1 folds in the self-loop.
__global__ __launch_bounds__(256) void scan1(const int* __restrict__ deg,
                                             int* __restrict__ row_start,
                                             int* __restrict__ bsum) {
    __shared__ int ts[256];
    int t = threadIdx.x;
    int base = blockIdx.x * 1024 + t * 4;
    int v0 = (base + 0 < NN) ? deg[base + 0] + 1 : 0;
    int v1 = (base + 1 < NN) ? deg[base + 1] + 1 : 0;
    int v2 = (base + 2 < NN) ? deg[base + 2] + 1 : 0;
    int v3 = (base + 3 < NN) ? deg[base + 3] + 1 : 0;
    int s = v0 + v1 + v2 + v3;
    ts[t] = s;
    __syncthreads();
#pragma unroll
    for (int off = 1; off < 256; off <<= 1) {
        int add = (t >= off) ? ts[t - off] : 0;
        __syncthreads();
        ts[t] += add;
        __syncthreads();
    }
    int run = ts[t] - s;
    if (t == 255) bsum[blockIdx.x] = ts[255];
    if (base + 0 < NN) { row_start[base + 0] = run; run += v0; }
    if (base + 1 < NN) { row_start[base + 1] = run; run += v1; }
    if (base + 2 < NN) { row_start[base + 2] = run; run += v2; }
    if (base + 3 < NN) { row_start[base + 3] = run; run += v3; }
}

__global__ __launch_bounds__(64) void scan2(int* __restrict__ bsum, int* __restrict__ row_start) {
    int t = threadIdx.x;
    int orig = (t < SCAN_NB) ? bsum[t] : 0;
    int v = orig;
#pragma unroll
    for (int off = 1; off < 64; off <<= 1) {
        int u = __shfl_up(v, off);
        if (t >= off) v += u;
    }
    if (t < SCAN_NB) bsum[t] = v - orig;
    if (t == SCAN_NB - 1) row_start[NN] = v;
}

__global__ void scan3(int* __restrict__ row_start, const int* __restrict__ bsum) {
    int i = blockIdx.x * blockDim.x + threadIdx.x;
    if (i < NN) row_start[i] += bsum[i >> 10];
}

// final CSR scatter over partitioned edges (localized windows) + self-loops
// folded into the tail of the same grid.
#define SF_EDGE_T (NE / 4)                 // 200000 threads handling 4 edges each
__global__ void scatter_final(const int2* __restrict__ epart, const int* __restrict__ row_start,
                              int* __restrict__ wcount, int* __restrict__ ssrc) {
    int idx = blockIdx.x * blockDim.x + threadIdx.x;
    if (idx < SF_EDGE_T) {
        int j = idx * 4;
        int4 a = *(const int4*)(epart + j);
        int4 b = *(const int4*)(epart + j + 2);
        int p0 = atomicAdd(&wcount[a.x], 1);
        int p1 = atomicAdd(&wcount[a.z], 1);
        int p2 = atomicAdd(&wcount[b.x], 1);
        int p3 = atomicAdd(&wcount[b.z], 1);
        ssrc[row_start[a.x] + p0] = a.y;
        ssrc[row_start[a.z] + p1] = a.w;
        ssrc[row_start[b.x] + p2] = b.y;
        ssrc[row_start[b.z] + p3] = b.w;
    } else {
        int n = idx - SF_EDGE_T;
        if (n < NN) {
            int p = atomicAdd(&wcount[n], 1);
            ssrc[row_start[n] + p] = n;
        }
    }
}

// ---------------- GEMM: 8x8 register tile, A via LDS, W via L2 w/ prefetch ----------------
// W streams 36KB/block from L2 (> 32KB L1, no reuse): R16 diagnosis says the
// k4 loop stalled ~300cy/iter waiting on W loads at 1.15 waves/SIMD. Fix:
// one-deep register double-buffer - issue k4+1's 8 W-loads before k4's 256
// FMAs (512cy of cover). Conv layers (outh): fp16 messages (R13).
__global__ __launch_bounds__(192) void gemm96(const float* __restrict__ A,
                                              const float* __restrict__ W,
                                              const float* __restrict__ bias,
                                              float* __restrict__ outf,
                                              __half* __restrict__ outh,
                                              const float* __restrict__ att_s,
                                              const float* __restrict__ att_d,
                                              float* __restrict__ as_out,
                                              float* __restrict__ ad_out) {
    __shared__ float4 As4[GROWS * RS4];          // 128 rows x 24 f4 (+1 pad) = 50KB
    int t = threadIdx.x;
    const float4* A4 = (const float4*)A;
#pragma unroll
    for (int i = 0; i < 16; i++) {
        int idx = t + 192 * i;                   // 0..3071 = [128 rows][24 c4]
        int row = idx / 24, c4 = idx % 24;
        int grow = blockIdx.x * GROWS + row;
        As4[row * RS4 + c4] = (grow < NN) ? A4[(size_t)grow * 24 + c4]
                                          : make_float4(0.f, 0.f, 0.f, 0.f);
    }
    __syncthreads();

    int rowg = t / 12;                           // 0..15 -> rows rowg+16*i, i<8
    int colg = t % 12;                           // 0..11 -> cols colg*8..+7
    const float4* __restrict__ W4 = (const float4*)W;   // [k][24 f4]
    float4 acc[8][2];
#pragma unroll
    for (int i = 0; i < 8; i++) {
        acc[i][0] = make_float4(0.f, 0.f, 0.f, 0.f);
        acc[i][1] = make_float4(0.f, 0.f, 0.f, 0.f);
    }

    float4 w_cur[8];
#pragma unroll
    for (int kk = 0; kk < 4; kk++) {
        w_cur[kk * 2]     = W4[kk * 24 + colg * 2];
        w_cur[kk * 2 + 1] = W4[kk * 24 + colg * 2 + 1];
    }

#pragma unroll 1
    for (int k4 = 0; k4 < 24; k4++) {
        float4 w_nxt[8];
        if (k4 < 23) {
#pragma unroll
            for (int kk = 0; kk < 4; kk++) {
                w_nxt[kk * 2]     = W4[(4 * (k4 + 1) + kk) * 24 + colg * 2];
                w_nxt[kk * 2 + 1] = W4[(4 * (k4 + 1) + kk) * 24 + colg * 2 + 1];
            }
        }
        float4 a4[8];
#pragma unroll
        for (int i = 0; i < 8; i++) a4[i] = As4[(rowg + 16 * i) * RS4 + k4];
#pragma unroll
        for (int kk = 0; kk < 4; kk++) {
            float4 w0 = w_cur[kk * 2];
            float4 w1 = w_cur[kk * 2 + 1];
#pragma unroll
            for (int i = 0; i < 8; i++) {
                float a = (kk == 0) ? a4[i].x : (kk == 1) ? a4[i].y
                         : (kk == 2) ? a4[i].z : a4[i].w;
                acc[i][0].x += a * w0.x; acc[i][0].y += a * w0.y;
                acc[i][0].z += a * w0.z; acc[i][0].w += a * w0.w;
                acc[i][1].x += a * w1.x; acc[i][1].y += a * w1.y;
                acc[i][1].z += a * w1.z; acc[i][1].w += a * w1.w;
            }
        }
#pragma unroll
        for (int i = 0; i < 8; i++) w_cur[i] = w_nxt[i];
    }

    if (bias) {
        float4 b0 = ((const float4*)bias)[colg * 2];
        float4 b1 = ((const float4*)bias)[colg * 2 + 1];
#pragma unroll
        for (int i = 0; i < 8; i++) {
            acc[i][0].x += b0.x; acc[i][0].y += b0.y; acc[i][0].z += b0.z; acc[i][0].w += b0.w;
            acc[i][1].x += b1.x; acc[i][1].y += b1.y; acc[i][1].z += b1.z; acc[i][1].w += b1.w;
        }
    }
    if (outf) {
        float4* out4 = (float4*)outf;
#pragma unroll
        for (int i = 0; i < 8; i++) {
            int grow = blockIdx.x * GROWS + rowg + 16 * i;
            if (grow < NN) {
                out4[(size_t)grow * 24 + colg * 2] = acc[i][0];
                out4[(size_t)grow * 24 + colg * 2 + 1] = acc[i][1];
            }
        }
    }
    if (outh) {
        uint4* oh = (uint4*)outh;                // 12 uint4 (8 halves each) per row
#pragma unroll
        for (int i = 0; i < 8; i++) {
            int grow = blockIdx.x * GROWS + rowg + 16 * i;
            if (grow < NN) {
                __half2 p0 = __float22half2_rn(make_float2(acc[i][0].x, acc[i][0].y));
                __half2 p1 = __float22half2_rn(make_float2(acc[i][0].z, acc[i][0].w));
                __half2 p2 = __float22half2_rn(make_float2(acc[i][1].x, acc[i][1].y));
                __half2 p3 = __float22half2_rn(make_float2(acc[i][1].z, acc[i][1].w));
                uint4 v;
                v.x = *(unsigned int*)&p0;
                v.y = *(unsigned int*)&p1;
                v.z = *(unsigned int*)&p2;
                v.w = *(unsigned int*)&p3;
                oh[(size_t)grow * 12 + colg] = v;
            }
        }
    }

    if (att_s != nullptr) {
        __syncthreads();                         // As dead -> reuse for output tile
#pragma unroll
        for (int i = 0; i < 8; i++) {
            int row = rowg + 16 * i;
            As4[row * RS4 + colg * 2] = acc[i][0];
            As4[row * RS4 + colg * 2 + 1] = acc[i][1];
        }
        __syncthreads();
        for (int task = t; task < GROWS * HEADS; task += 192) {
            int row = task >> 2, hh = task & 3;
            int grow = blockIdx.x * GROWS + row;
            if (grow < NN) {
                const float4* av = (const float4*)(att_s + hh * DHH);
                const float4* bv = (const float4*)(att_d + hh * DHH);
                const float4* hr = &As4[row * RS4 + hh * 6];
                float s1 = 0.f, s2 = 0.f;
#pragma unroll
                for (int k = 0; k < 6; k++) {
                    float4 v = hr[k], a = av[k], d = bv[k];
                    s1 += v.x * a.x + v.y * a.y + v.z * a.z + v.w * a.w;
                    s2 += v.x * d.x + v.y * d.y + v.z * d.z + v.w * d.w;
                }
                as_out[grow * 4 + hh] = s1;
                ad_out[grow * 4 + hh] = s2;
            }
        }
    }
}

// ---------------- branchless softmax aggregation + bias + BN + ReLU ----------------
// 24 threads/node (4 halves = 8B each), 8 nodes/block, 4-way unroll. Messages
// gathered fp16 (halves random-gather bytes); weights/denoms fp32 (exact).
__global__ __launch_bounds__(192) void aggregate(const __half* __restrict__ hBh,
                                                 const int* __restrict__ row_start,
                                                 const int* __restrict__ ssrc,
                                                 const float* __restrict__ asv,
                                                 const float* __restrict__ adv,
                                                 const float* __restrict__ bc,
                                                 const float* __restrict__ gamma,
                                                 const float* __restrict__ beta,
                                                 const float* __restrict__ mean,
                                                 const float* __restrict__ var,
                                                 float* __restrict__ out) {
    int t = threadIdx.x;
    int n = blockIdx.x * 8 + t / 24;
    int q = t % 24;
    int hh = q / 6;
    int start = row_start[n];
    int end = row_start[n + 1];
    float ad = adv[n * 4 + hh];
    const uint2* __restrict__ hB8 = (const uint2*)hBh;   // 24 x 8B per row

#define GATHER_ACC(U, WW, AX)                                            \
    {                                                                    \
        __half2 ha = *(__half2*)&U.x;                                    \
        __half2 hb = *(__half2*)&U.y;                                    \
        float2 fa = __half22float2(ha);                                  \
        float2 fb = __half22float2(hb);                                  \
        AX.x += WW * fa.x; AX.y += WW * fa.y;                            \
        AX.z += WW * fb.x; AX.w += WW * fb.y;                            \
    }

    float4 a0 = make_float4(0,0,0,0), a1 = a0, a2 = a0, a3 = a0;
    float s0 = 0.f, s1 = 0.f, s2 = 0.f, s3 = 0.f;
    int j = start;
    for (; j + 3 < end; j += 4) {
        int i0 = ssrc[j], i1 = ssrc[j+1], i2 = ssrc[j+2], i3 = ssrc[j+3];
        uint2 u0 = hB8[i0 * 24 + q];
        uint2 u1 = hB8[i1 * 24 + q];
        uint2 u2 = hB8[i2 * 24 + q];
        uint2 u3 = hB8[i3 * 24 + q];
        float e0 = asv[i0 * 4 + hh] + ad; e0 = (e0 >= 0.f) ? e0 : 0.2f * e0;
        float e1 = asv[i1 * 4 + hh] + ad; e1 = (e1 >= 0.f) ? e1 : 0.2f * e1;
        float e2 = asv[i2 * 4 + hh] + ad; e2 = (e2 >= 0.f) ? e2 : 0.2f * e2;
        float e3 = asv[i3 * 4 + hh] + ad; e3 = (e3 >= 0.f) ? e3 : 0.2f * e3;
        float w0 = __expf(fminf(e0, 80.f)), w1 = __expf(fminf(e1, 80.f));
        float w2 = __expf(fminf(e2, 80.f)), w3 = __expf(fminf(e3, 80.f));
        GATHER_ACC(u0, w0, a0) s0 += w0;
        GATHER_ACC(u1, w1, a1) s1 += w1;
        GATHER_ACC(u2, w2, a2) s2 += w2;
        GATHER_ACC(u3, w3, a3) s3 += w3;
    }
    for (; j < end; j++) {
        int i0 = ssrc[j];
        uint2 u0 = hB8[i0 * 24 + q];
        float e0 = asv[i0 * 4 + hh] + ad; e0 = (e0 >= 0.f) ? e0 : 0.2f * e0;
        float w0 = __expf(fminf(e0, 80.f));
        GATHER_ACC(u0, w0, a0) s0 += w0;
    }
#undef GATHER_ACC
    float4 acc;
    acc.x = (a0.x + a1.x) + (a2.x + a3.x);
    acc.y = (a0.y + a1.y) + (a2.y + a3.y);
    acc.z = (a0.z + a1.z) + (a2.z + a3.z);
    acc.w = (a0.w + a1.w) + (a2.w + a3.w);
    float den = (s0 + s1) + (s2 + s3) + 1e-16f;

    float4 b = ((const float4*)bc)[q];
    float4 mu = ((const float4*)mean)[q];
    float4 vr = ((const float4*)var)[q];
    float4 g = ((const float4*)gamma)[q];
    float4 bt = ((const float4*)beta)[q];
    float4 o;
    o.x = fmaxf((acc.x / den + b.x - mu.x) * (1.0f / sqrtf(vr.x + 1e-5f)) * g.x + bt.x, 0.f);
    o.y = fmaxf((acc.y / den + b.y - mu.y) * (1.0f / sqrtf(vr.y + 1e-5f)) * g.y + bt.y, 0.f);
    o.z = fmaxf((acc.z / den + b.z - mu.z) * (1.0f / sqrtf(vr.z + 1e-5f)) * g.z + bt.z, 0.f);
    o.w = fmaxf((acc.w / den + b.w - mu.w) * (1.0f / sqrtf(vr.w + 1e-5f)) * g.w + bt.w, 0.f);
    ((float4*)out)[n * 24 + q] = o;
}

// ---------------- segment bounds for sorted batch ----------------
__global__ void seg_bounds(const int* __restrict__ batch, int* __restrict__ gstart,
                           int* __restrict__ gend) {
    int n = blockIdx.x * blockDim.x + threadIdx.x;
    if (n >= NN) return;
    int b = batch[n];
    if (n == 0 || batch[n - 1] != b) gstart[b] = n;
    if (n == NN - 1 || batch[n + 1] != b) gend[b] = n + 1;
}

// ---------------- global mean pool (atomic-free; batch is sorted) ----------------
__global__ void pool_kernel(const float* __restrict__ h, const int* __restrict__ gstart,
                            const int* __restrict__ gend, float* __restrict__ pooled) {
    int i = blockIdx.x * blockDim.x + threadIdx.x;
    if (i >= GG * DD) return;
    int g = i / DD;
    int d = i - g * DD;
    int s = gstart[g], e = gend[g];
    float acc = 0.f;
    for (int n = s; n < e; n++) acc += h[(size_t)n * DD + d];
    pooled[i] = acc / fmaxf((float)(e - s), 1.0f);
}

// ---------------- output MLP: one block per graph ----------------
__global__ __launch_bounds__(128) void mlp_kernel(const float* __restrict__ pooled,
                                                  const float* __restrict__ W1, const float* __restrict__ b1,
                                                  const float* __restrict__ W2, const float* __restrict__ b2,
                                                  const float* __restrict__ W3, const float* __restrict__ b3,
                                                  float* __restrict__ out) {
    __shared__ float p[96], z1[96], z2[48];
    int g = blockIdx.x, t = threadIdx.x;
    if (t < 96) p[t] = pooled[g * 96 + t];
    __syncthreads();
    if (t < 96) {
        float s = b1[t];
#pragma unroll
        for (int k = 0; k < 96; k++) s += p[k] * W1[k * 96 + t];
        z1[t] = fmaxf(s, 0.f);
    }
    __syncthreads();
    if (t < 48) {
        float s = b2[t];
#pragma unroll
        for (int k = 0; k < 96; k++) s += z1[k] * W2[k * 48 + t];
        z2[t] = fmaxf(s, 0.f);
    }
    __syncthreads();
    if (t == 0) {
        float s = b3[0];
        for (int k = 0; k < 48; k++) s += z2[k] * W3[k];
        out[g] = s;
    }
}

extern "C" void kernel_launch(void* const* d_in, const int* in_sizes, int n_in,
                              void* d_out, int out_size, void* d_ws, size_t ws_size,
                              hipStream_t stream) {
    const float* x        = (const float*)d_in[0];
    const int*   ei       = (const int*)d_in[1];
    const int*   batch    = (const int*)d_in[2];
    const float* Wp       = (const float*)d_in[3];
    const float* bp       = (const float*)d_in[4];
    const float* Wc       = (const float*)d_in[5];
    const float* att_src  = (const float*)d_in[6];
    const float* att_dst  = (const float*)d_in[7];
    const float* bc       = (const float*)d_in[8];
    const float* bn_gamma = (const float*)d_in[9];
    const float* bn_beta  = (const float*)d_in[10];
    const float* bn_mean  = (const float*)d_in[11];
    const float* bn_var   = (const float*)d_in[12];
    const float* W1       = (const float*)d_in[13];
    const float* b1       = (const float*)d_in[14];
    const float* W2       = (const float*)d_in[15];
    const float* b2       = (const float*)d_in[16];
    const float* W3       = (const float*)d_in[17];
    const float* b3       = (const float*)d_in[18];
    float* out = (float*)d_out;

    char* ws = (char*)d_ws;
    auto alloc = [&](size_t bytes) {
        void* p = (void*)ws;
        ws += (bytes + 255) & ~(size_t)255;
        return p;
    };
    float*  hA        = (float*)alloc((size_t)NN * DD * 4);
    __half* hBh       = (__half*)alloc((size_t)NN * DD * 2);
    float*  as_       = (float*)alloc((size_t)NN * HEADS * 4);
    float*  ad_       = (float*)alloc((size_t)NN * HEADS * 4);
    char*   z0        = ws;                               // ---- zeroed region start
    int*    deg       = (int*)alloc((size_t)NN * 4);
    int*    wcount    = (int*)alloc((size_t)NN * 4);
    int*    gstart    = (int*)alloc((size_t)GG * 4);
    int*    gend      = (int*)alloc((size_t)GG * 4);
    int*    gsize     = (int*)alloc((size_t)NB * 4);
    char*   z1        = ws;                               // ---- zeroed region end
    int*    cursor    = (int*)alloc((size_t)NB * 4);
    int*    row_start = (int*)alloc((size_t)(NN + 1) * 4);
    int*    bsum      = (int*)alloc((size_t)SCAN_NB * 4);
    int*    ssrc      = (int*)alloc((size_t)ETOT * 4);
    int2*   epart     = (int2*)alloc((size_t)NE * 8);
    float*  pooled    = (float*)alloc((size_t)GG * DD * 4);

    hipMemsetAsync(z0, 0, (size_t)(z1 - z0), stream);

    bucket_count<<<PART_NBLK, 256, 0, stream>>>(ei, gsize);
    bucket_scan<<<1, 256, 0, stream>>>(gsize, cursor);
    bucket_partition<<<PART_NBLK, 256, 0, stream>>>(ei, cursor, epart);
    count_deg2<<<(NE / 4 + 255) / 256, 256, 0, stream>>>(epart, deg);
    scan1<<<SCAN_NB, 256, 0, stream>>>(deg, row_start, bsum);
    scan2<<<1, 64, 0, stream>>>(bsum, row_start);
    scan3<<<(NN + 255) / 256, 256, 0, stream>>>(row_start, bsum);
    scatter_final<<<(SF_EDGE_T + NN + 255) / 256, 256, 0, stream>>>(epart, row_start, wcount, ssrc);
    seg_bounds<<<(NN + 255) / 256, 256, 0, stream>>>(batch, gstart, gend);

    const int gemm_grid = (NN + GROWS - 1) / GROWS;
    gemm96<<<gemm_grid, 192, 0, stream>>>(x, Wp, bp, hA, nullptr,
                                          nullptr, nullptr, nullptr, nullptr);

    for (int l = 0; l < NL; l++) {
        gemm96<<<gemm_grid, 192, 0, stream>>>(hA, Wc + (size_t)l * DD * DD, nullptr,
                                              nullptr, hBh,
                                              att_src + (size_t)l * HEADS * DHH,
                                              att_dst + (size_t)l * HEADS * DHH, as_, ad_);
        aggregate<<<NN / 8, 192, 0, stream>>>(hBh, row_start, ssrc, as_, ad_,
                                              bc + (size_t)l * DD,
                                              bn_gamma + (size_t)l * DD, bn_beta + (size_t)l * DD,
                                              bn_mean + (size_t)l * DD, bn_var + (size_t)l * DD,
                                              hA);
    }

    pool_kernel<<<(GG * DD + 255) / 256, 256, 0, stream>>>(hA, gstart, gend, pooled);
    mlp_kernel<<<GG, 128, 0, stream>>>(pooled, W1, b1, W2, b2, W3, b3, out);
}

// Round 18
// 319.670 us; speedup vs baseline: 1.0451x; 1.0451x over previous
//
#include <hip/hip_runtime.h>
#include <hip/hip_fp16.h>

#define NN 50000
#define NE 800000
#define ETOT (NE + NN)
#define GG 1000
#define DD 96
#define HEADS 4
#define DHH 24
#define NL 3
#define SCAN_NB 49     // ceil(NN / 1024)
#define NB 256         // dst buckets (dst>>8): 196 used
#define EPB 4096       // edges per partition block (R17: 2048 regressed; 4096 proven)
#define PART_NBLK ((NE + EPB - 1) / EPB)   // 196
#define GROWS 128      // gemm rows per block (R14/R16-proven; 64 & W-prefetch both regressed)
#define RS4 25         // A-tile row stride in float4 (100 floats; 100%32=4 banks)

// ---------------- bucket partition of edges by dst>>8 ----------------
__global__ __launch_bounds__(256) void bucket_count(const int* __restrict__ ei,
                                                    int* __restrict__ gsize) {
    __shared__ int lh[NB];
    int t = threadIdx.x;
    lh[t] = 0;
    __syncthreads();
    int base = blockIdx.x * EPB + t * 16;
    for (int k = 0; k < 16; k += 4) {
        int j = base + k;
        if (j + 3 < NE) {
            int4 d = *(const int4*)(ei + NE + j);
            atomicAdd(&lh[d.x >> 8], 1);
            atomicAdd(&lh[d.y >> 8], 1);
            atomicAdd(&lh[d.z >> 8], 1);
            atomicAdd(&lh[d.w >> 8], 1);
        } else {
            for (int q = 0; q < 4 && j + q < NE; q++)
                atomicAdd(&lh[ei[NE + j + q] >> 8], 1);
        }
    }
    __syncthreads();
    if (lh[t]) atomicAdd(&gsize[t], lh[t]);
}

__global__ __launch_bounds__(256) void bucket_scan(const int* __restrict__ gsize,
                                                   int* __restrict__ cursor) {
    __shared__ int ts[NB];
    int t = threadIdx.x;
    int v = gsize[t];
    ts[t] = v;
    __syncthreads();
#pragma unroll
    for (int off = 1; off < NB; off <<= 1) {
        int add = (t >= off) ? ts[t - off] : 0;
        __syncthreads();
        ts[t] += add;
        __syncthreads();
    }
    cursor[t] = ts[t] - v;   // exclusive
}

// R15 lesson: deg atomics do NOT belong here (original edge order = random
// scatter, +15us). count_deg2 runs over the PARTITIONED array instead.
__global__ __launch_bounds__(256) void bucket_partition(const int* __restrict__ ei,
                                                        int* __restrict__ cursor,
                                                        int2* __restrict__ epart) {
    __shared__ int lh[NB], lbase[NB];
    int t = threadIdx.x;
    lh[t] = 0;
    __syncthreads();
    int base = blockIdx.x * EPB + t * 16;
    for (int k = 0; k < 16; k += 4) {       // pass 1: block histogram
        int j = base + k;
        if (j + 3 < NE) {
            int4 d = *(const int4*)(ei + NE + j);
            atomicAdd(&lh[d.x >> 8], 1);
            atomicAdd(&lh[d.y >> 8], 1);
            atomicAdd(&lh[d.z >> 8], 1);
            atomicAdd(&lh[d.w >> 8], 1);
        } else {
            for (int q = 0; q < 4 && j + q < NE; q++)
                atomicAdd(&lh[ei[NE + j + q] >> 8], 1);
        }
    }
    __syncthreads();
    int cnt = lh[t];
    if (cnt) lbase[t] = atomicAdd(&cursor[t], cnt);  // reserve contiguous range
    lh[t] = 0;                                       // reuse as rank counter
    __syncthreads();
    for (int k = 0; k < 16; k += 4) {       // pass 2: grouped writes
        int j = base + k;
        if (j + 3 < NE) {
            int4 s = *(const int4*)(ei + j);
            int4 d = *(const int4*)(ei + NE + j);
            int b0 = d.x >> 8, b1 = d.y >> 8, b2 = d.z >> 8, b3 = d.w >> 8;
            int r0 = atomicAdd(&lh[b0], 1);
            int r1 = atomicAdd(&lh[b1], 1);
            int r2 = atomicAdd(&lh[b2], 1);
            int r3 = atomicAdd(&lh[b3], 1);
            epart[lbase[b0] + r0] = make_int2(d.x, s.x);
            epart[lbase[b1] + r1] = make_int2(d.y, s.y);
            epart[lbase[b2] + r2] = make_int2(d.z, s.z);
            epart[lbase[b3] + r3] = make_int2(d.w, s.w);
        } else {
            for (int q = 0; q < 4 && j + q < NE; q++) {
                int dd = ei[NE + j + q], ss = ei[j + q];
                int b = dd >> 8;
                int r = atomicAdd(&lh[b], 1);
                epart[lbase[b] + r] = make_int2(dd, ss);
            }
        }
    }
}

// ---------------- degree count on partitioned edges (localized atomics) ----------------
__global__ void count_deg2(const int2* __restrict__ epart, int* __restrict__ deg) {
    int j = (blockIdx.x * blockDim.x + threadIdx.x) * 4;
    if (j + 3 < NE) {
        int4 a = *(const int4*)(epart + j);       // (d,s,d,s)
        int4 b = *(const int4*)(epart + j + 2);
        atomicAdd(&deg[a.x], 1);
        atomicAdd(&deg[a.z], 1);
        atomicAdd(&deg[b.x], 1);
        atomicAdd(&deg[b.z], 1);
    } else {
        for (int k = 0; k < 4 && j + k < NE; k++) atomicAdd(&deg[epart[j + k].x], 1);
    }
}

// hierarchical scan, phase 1: deg[i]+1 folds in the self-loop.
__global__ __launch_bounds__(256) void scan1(const int* __restrict__ deg,
                                             int* __restrict__ row_start,
                                             int* __restrict__ bsum) {
    __shared__ int ts[256];
    int t = threadIdx.x;
    int base = blockIdx.x * 1024 + t * 4;
    int v0 = (base + 0 < NN) ? deg[base + 0] + 1 : 0;
    int v1 = (base + 1 < NN) ? deg[base + 1] + 1 : 0;
    int v2 = (base + 2 < NN) ? deg[base + 2] + 1 : 0;
    int v3 = (base + 3 < NN) ? deg[base + 3] + 1 : 0;
    int s = v0 + v1 + v2 + v3;
    ts[t] = s;
    __syncthreads();
#pragma unroll
    for (int off = 1; off < 256; off <<= 1) {
        int add = (t >= off) ? ts[t - off] : 0;
        __syncthreads();
        ts[t] += add;
        __syncthreads();
    }
    int run = ts[t] - s;
    if (t == 255) bsum[blockIdx.x] = ts[255];
    if (base + 0 < NN) { row_start[base + 0] = run; run += v0; }
    if (base + 1 < NN) { row_start[base + 1] = run; run += v1; }
    if (base + 2 < NN) { row_start[base + 2] = run; run += v2; }
    if (base + 3 < NN) { row_start[base + 3] = run; run += v3; }
}

__global__ __launch_bounds__(64) void scan2(int* __restrict__ bsum, int* __restrict__ row_start) {
    int t = threadIdx.x;
    int orig = (t < SCAN_NB) ? bsum[t] : 0;
    int v = orig;
#pragma unroll
    for (int off = 1; off < 64; off <<= 1) {
        int u = __shfl_up(v, off);
        if (t >= off) v += u;
    }
    if (t < SCAN_NB) bsum[t] = v - orig;
    if (t == SCAN_NB - 1) row_start[NN] = v;
}

__global__ void scan3(int* __restrict__ row_start, const int* __restrict__ bsum) {
    int i = blockIdx.x * blockDim.x + threadIdx.x;
    if (i < NN) row_start[i] += bsum[i >> 10];
}

// final CSR scatter over partitioned edges (localized windows) + self-loops
// folded into the tail of the same grid.
#define SF_EDGE_T (NE / 4)                 // 200000 threads handling 4 edges each
__global__ void scatter_final(const int2* __restrict__ epart, const int* __restrict__ row_start,
                              int* __restrict__ wcount, int* __restrict__ ssrc) {
    int idx = blockIdx.x * blockDim.x + threadIdx.x;
    if (idx < SF_EDGE_T) {
        int j = idx * 4;
        int4 a = *(const int4*)(epart + j);
        int4 b = *(const int4*)(epart + j + 2);
        int p0 = atomicAdd(&wcount[a.x], 1);
        int p1 = atomicAdd(&wcount[a.z], 1);
        int p2 = atomicAdd(&wcount[b.x], 1);
        int p3 = atomicAdd(&wcount[b.z], 1);
        ssrc[row_start[a.x] + p0] = a.y;
        ssrc[row_start[a.z] + p1] = a.w;
        ssrc[row_start[b.x] + p2] = b.y;
        ssrc[row_start[b.z] + p3] = b.w;
    } else {
        int n = idx - SF_EDGE_T;
        if (n < NN) {
            int p = atomicAdd(&wcount[n], 1);
            ssrc[row_start[n] + p] = n;
        }
    }
}

// ---------------- GEMM: 8x8 register tile, A via LDS, W via L1 ----------------
// GROWS=128, plain k4 loop (R17: W reg-double-buffer regressed - W is L1-
// broadcast-shared by 16 rowg groups, not a stall source; the unroll-1 dbuf
// just added 32 v_mov/iter + VGPR pressure). W via global/L1 (R9: LDS pipe is
// shared 1-per-CU, W must NOT come from LDS). Conv layers: fp16 messages (R13).
__global__ __launch_bounds__(192) void gemm96(const float* __restrict__ A,
                                              const float* __restrict__ W,
                                              const float* __restrict__ bias,
                                              float* __restrict__ outf,
                                              __half* __restrict__ outh,
                                              const float* __restrict__ att_s,
                                              const float* __restrict__ att_d,
                                              float* __restrict__ as_out,
                                              float* __restrict__ ad_out) {
    __shared__ float4 As4[GROWS * RS4];          // 128 rows x 24 f4 (+1 pad) = 50KB
    int t = threadIdx.x;
    const float4* A4 = (const float4*)A;
#pragma unroll
    for (int i = 0; i < 16; i++) {
        int idx = t + 192 * i;                   // 0..3071 = [128 rows][24 c4]
        int row = idx / 24, c4 = idx % 24;
        int grow = blockIdx.x * GROWS + row;
        As4[row * RS4 + c4] = (grow < NN) ? A4[(size_t)grow * 24 + c4]
                                          : make_float4(0.f, 0.f, 0.f, 0.f);
    }
    __syncthreads();

    int rowg = t / 12;                           // 0..15 -> rows rowg+16*i, i<8
    int colg = t % 12;                           // 0..11 -> cols colg*8..+7
    const float4* __restrict__ W4 = (const float4*)W;   // [k][24 f4]
    float4 acc[8][2];
#pragma unroll
    for (int i = 0; i < 8; i++) {
        acc[i][0] = make_float4(0.f, 0.f, 0.f, 0.f);
        acc[i][1] = make_float4(0.f, 0.f, 0.f, 0.f);
    }

#pragma unroll 1
    for (int k4 = 0; k4 < 24; k4++) {
        float4 a4[8];
#pragma unroll
        for (int i = 0; i < 8; i++) a4[i] = As4[(rowg + 16 * i) * RS4 + k4];
#pragma unroll
        for (int kk = 0; kk < 4; kk++) {
            int k = 4 * k4 + kk;
            float4 w0 = W4[k * 24 + colg * 2];
            float4 w1 = W4[k * 24 + colg * 2 + 1];
#pragma unroll
            for (int i = 0; i < 8; i++) {
                float a = (kk == 0) ? a4[i].x : (kk == 1) ? a4[i].y
                         : (kk == 2) ? a4[i].z : a4[i].w;
                acc[i][0].x += a * w0.x; acc[i][0].y += a * w0.y;
                acc[i][0].z += a * w0.z; acc[i][0].w += a * w0.w;
                acc[i][1].x += a * w1.x; acc[i][1].y += a * w1.y;
                acc[i][1].z += a * w1.z; acc[i][1].w += a * w1.w;
            }
        }
    }

    if (bias) {
        float4 b0 = ((const float4*)bias)[colg * 2];
        float4 b1 = ((const float4*)bias)[colg * 2 + 1];
#pragma unroll
        for (int i = 0; i < 8; i++) {
            acc[i][0].x += b0.x; acc[i][0].y += b0.y; acc[i][0].z += b0.z; acc[i][0].w += b0.w;
            acc[i][1].x += b1.x; acc[i][1].y += b1.y; acc[i][1].z += b1.z; acc[i][1].w += b1.w;
        }
    }
    if (outf) {
        float4* out4 = (float4*)outf;
#pragma unroll
        for (int i = 0; i < 8; i++) {
            int grow = blockIdx.x * GROWS + rowg + 16 * i;
            if (grow < NN) {
                out4[(size_t)grow * 24 + colg * 2] = acc[i][0];
                out4[(size_t)grow * 24 + colg * 2 + 1] = acc[i][1];
            }
        }
    }
    if (outh) {
        uint4* oh = (uint4*)outh;                // 12 uint4 (8 halves each) per row
#pragma unroll
        for (int i = 0; i < 8; i++) {
            int grow = blockIdx.x * GROWS + rowg + 16 * i;
            if (grow < NN) {
                __half2 p0 = __float22half2_rn(make_float2(acc[i][0].x, acc[i][0].y));
                __half2 p1 = __float22half2_rn(make_float2(acc[i][0].z, acc[i][0].w));
                __half2 p2 = __float22half2_rn(make_float2(acc[i][1].x, acc[i][1].y));
                __half2 p3 = __float22half2_rn(make_float2(acc[i][1].z, acc[i][1].w));
                uint4 v;
                v.x = *(unsigned int*)&p0;
                v.y = *(unsigned int*)&p1;
                v.z = *(unsigned int*)&p2;
                v.w = *(unsigned int*)&p3;
                oh[(size_t)grow * 12 + colg] = v;
            }
        }
    }

    if (att_s != nullptr) {
        __syncthreads();                         // As dead -> reuse for output tile
#pragma unroll
        for (int i = 0; i < 8; i++) {
            int row = rowg + 16 * i;
            As4[row * RS4 + colg * 2] = acc[i][0];
            As4[row * RS4 + colg * 2 + 1] = acc[i][1];
        }
        __syncthreads();
        for (int task = t; task < GROWS * HEADS; task += 192) {
            int row = task >> 2, hh = task & 3;
            int grow = blockIdx.x * GROWS + row;
            if (grow < NN) {
                const float4* av = (const float4*)(att_s + hh * DHH);
                const float4* bv = (const float4*)(att_d + hh * DHH);
                const float4* hr = &As4[row * RS4 + hh * 6];
                float s1 = 0.f, s2 = 0.f;
#pragma unroll
                for (int k = 0; k < 6; k++) {
                    float4 v = hr[k], a = av[k], d = bv[k];
                    s1 += v.x * a.x + v.y * a.y + v.z * a.z + v.w * a.w;
                    s2 += v.x * d.x + v.y * d.y + v.z * d.z + v.w * d.w;
                }
                as_out[grow * 4 + hh] = s1;
                ad_out[grow * 4 + hh] = s2;
            }
        }
    }
}

// ---------------- branchless softmax aggregation + bias + BN + ReLU ----------------
// 24 threads/node (4 halves = 8B each), 8 nodes/block, 4-way unroll. Messages
// gathered fp16 (halves random-gather bytes); weights/denoms fp32 (exact).
__global__ __launch_bounds__(192) void aggregate(const __half* __restrict__ hBh,
                                                 const int* __restrict__ row_start,
                                                 const int* __restrict__ ssrc,
                                                 const float* __restrict__ asv,
                                                 const float* __restrict__ adv,
                                                 const float* __restrict__ bc,
                                                 const float* __restrict__ gamma,
                                                 const float* __restrict__ beta,
                                                 const float* __restrict__ mean,
                                                 const float* __restrict__ var,
                                                 float* __restrict__ out) {
    int t = threadIdx.x;
    int n = blockIdx.x * 8 + t / 24;
    int q = t % 24;
    int hh = q / 6;
    int start = row_start[n];
    int end = row_start[n + 1];
    float ad = adv[n * 4 + hh];
    const uint2* __restrict__ hB8 = (const uint2*)hBh;   // 24 x 8B per row

#define GATHER_ACC(U, WW, AX)                                            \
    {                                                                    \
        __half2 ha = *(__half2*)&U.x;                                    \
        __half2 hb = *(__half2*)&U.y;                                    \
        float2 fa = __half22float2(ha);                                  \
        float2 fb = __half22float2(hb);                                  \
        AX.x += WW * fa.x; AX.y += WW * fa.y;                            \
        AX.z += WW * fb.x; AX.w += WW * fb.y;                            \
    }

    float4 a0 = make_float4(0,0,0,0), a1 = a0, a2 = a0, a3 = a0;
    float s0 = 0.f, s1 = 0.f, s2 = 0.f, s3 = 0.f;
    int j = start;
    for (; j + 3 < end; j += 4) {
        int i0 = ssrc[j], i1 = ssrc[j+1], i2 = ssrc[j+2], i3 = ssrc[j+3];
        uint2 u0 = hB8[i0 * 24 + q];
        uint2 u1 = hB8[i1 * 24 + q];
        uint2 u2 = hB8[i2 * 24 + q];
        uint2 u3 = hB8[i3 * 24 + q];
        float e0 = asv[i0 * 4 + hh] + ad; e0 = (e0 >= 0.f) ? e0 : 0.2f * e0;
        float e1 = asv[i1 * 4 + hh] + ad; e1 = (e1 >= 0.f) ? e1 : 0.2f * e1;
        float e2 = asv[i2 * 4 + hh] + ad; e2 = (e2 >= 0.f) ? e2 : 0.2f * e2;
        float e3 = asv[i3 * 4 + hh] + ad; e3 = (e3 >= 0.f) ? e3 : 0.2f * e3;
        float w0 = __expf(fminf(e0, 80.f)), w1 = __expf(fminf(e1, 80.f));
        float w2 = __expf(fminf(e2, 80.f)), w3 = __expf(fminf(e3, 80.f));
        GATHER_ACC(u0, w0, a0) s0 += w0;
        GATHER_ACC(u1, w1, a1) s1 += w1;
        GATHER_ACC(u2, w2, a2) s2 += w2;
        GATHER_ACC(u3, w3, a3) s3 += w3;
    }
    for (; j < end; j++) {
        int i0 = ssrc[j];
        uint2 u0 = hB8[i0 * 24 + q];
        float e0 = asv[i0 * 4 + hh] + ad; e0 = (e0 >= 0.f) ? e0 : 0.2f * e0;
        float w0 = __expf(fminf(e0, 80.f));
        GATHER_ACC(u0, w0, a0) s0 += w0;
    }
#undef GATHER_ACC
    float4 acc;
    acc.x = (a0.x + a1.x) + (a2.x + a3.x);
    acc.y = (a0.y + a1.y) + (a2.y + a3.y);
    acc.z = (a0.z + a1.z) + (a2.z + a3.z);
    acc.w = (a0.w + a1.w) + (a2.w + a3.w);
    float den = (s0 + s1) + (s2 + s3) + 1e-16f;

    float4 b = ((const float4*)bc)[q];
    float4 mu = ((const float4*)mean)[q];
    float4 vr = ((const float4*)var)[q];
    float4 g = ((const float4*)gamma)[q];
    float4 bt = ((const float4*)beta)[q];
    float4 o;
    o.x = fmaxf((acc.x / den + b.x - mu.x) * (1.0f / sqrtf(vr.x + 1e-5f)) * g.x + bt.x, 0.f);
    o.y = fmaxf((acc.y / den + b.y - mu.y) * (1.0f / sqrtf(vr.y + 1e-5f)) * g.y + bt.y, 0.f);
    o.z = fmaxf((acc.z / den + b.z - mu.z) * (1.0f / sqrtf(vr.z + 1e-5f)) * g.z + bt.z, 0.f);
    o.w = fmaxf((acc.w / den + b.w - mu.w) * (1.0f / sqrtf(vr.w + 1e-5f)) * g.w + bt.w, 0.f);
    ((float4*)out)[n * 24 + q] = o;
}

// ---------------- segment bounds for sorted batch ----------------
__global__ void seg_bounds(const int* __restrict__ batch, int* __restrict__ gstart,
                           int* __restrict__ gend) {
    int n = blockIdx.x * blockDim.x + threadIdx.x;
    if (n >= NN) return;
    int b = batch[n];
    if (n == 0 || batch[n - 1] != b) gstart[b] = n;
    if (n == NN - 1 || batch[n + 1] != b) gend[b] = n + 1;
}

// ---------------- global mean pool (atomic-free; batch is sorted) ----------------
__global__ void pool_kernel(const float* __restrict__ h, const int* __restrict__ gstart,
                            const int* __restrict__ gend, float* __restrict__ pooled) {
    int i = blockIdx.x * blockDim.x + threadIdx.x;
    if (i >= GG * DD) return;
    int g = i / DD;
    int d = i - g * DD;
    int s = gstart[g], e = gend[g];
    float acc = 0.f;
    for (int n = s; n < e; n++) acc += h[(size_t)n * DD + d];
    pooled[i] = acc / fmaxf((float)(e - s), 1.0f);
}

// ---------------- output MLP: one block per graph ----------------
__global__ __launch_bounds__(128) void mlp_kernel(const float* __restrict__ pooled,
                                                  const float* __restrict__ W1, const float* __restrict__ b1,
                                                  const float* __restrict__ W2, const float* __restrict__ b2,
                                                  const float* __restrict__ W3, const float* __restrict__ b3,
                                                  float* __restrict__ out) {
    __shared__ float p[96], z1[96], z2[48];
    int g = blockIdx.x, t = threadIdx.x;
    if (t < 96) p[t] = pooled[g * 96 + t];
    __syncthreads();
    if (t < 96) {
        float s = b1[t];
#pragma unroll
        for (int k = 0; k < 96; k++) s += p[k] * W1[k * 96 + t];
        z1[t] = fmaxf(s, 0.f);
    }
    __syncthreads();
    if (t < 48) {
        float s = b2[t];
#pragma unroll
        for (int k = 0; k < 96; k++) s += z1[k] * W2[k * 48 + t];
        z2[t] = fmaxf(s, 0.f);
    }
    __syncthreads();
    if (t == 0) {
        float s = b3[0];
        for (int k = 0; k < 48; k++) s += z2[k] * W3[k];
        out[g] = s;
    }
}

extern "C" void kernel_launch(void* const* d_in, const int* in_sizes, int n_in,
                              void* d_out, int out_size, void* d_ws, size_t ws_size,
                              hipStream_t stream) {
    const float* x        = (const float*)d_in[0];
    const int*   ei       = (const int*)d_in[1];
    const int*   batch    = (const int*)d_in[2];
    const float* Wp       = (const float*)d_in[3];
    const float* bp       = (const float*)d_in[4];
    const float* Wc       = (const float*)d_in[5];
    const float* att_src  = (const float*)d_in[6];
    const float* att_dst  = (const float*)d_in[7];
    const float* bc       = (const float*)d_in[8];
    const float* bn_gamma = (const float*)d_in[9];
    const float* bn_beta  = (const float*)d_in[10];
    const float* bn_mean  = (const float*)d_in[11];
    const float* bn_var   = (const float*)d_in[12];
    const float* W1       = (const float*)d_in[13];
    const float* b1       = (const float*)d_in[14];
    const float* W2       = (const float*)d_in[15];
    const float* b2       = (const float*)d_in[16];
    const float* W3       = (const float*)d_in[17];
    const float* b3       = (const float*)d_in[18];
    float* out = (float*)d_out;

    char* ws = (char*)d_ws;
    auto alloc = [&](size_t bytes) {
        void* p = (void*)ws;
        ws += (bytes + 255) & ~(size_t)255;
        return p;
    };
    float*  hA        = (float*)alloc((size_t)NN * DD * 4);
    __half* hBh       = (__half*)alloc((size_t)NN * DD * 2);
    float*  as_       = (float*)alloc((size_t)NN * HEADS * 4);
    float*  ad_       = (float*)alloc((size_t)NN * HEADS * 4);
    char*   z0        = ws;                               // ---- zeroed region start
    int*    deg       = (int*)alloc((size_t)NN * 4);
    int*    wcount    = (int*)alloc((size_t)NN * 4);
    int*    gstart    = (int*)alloc((size_t)GG * 4);
    int*    gend      = (int*)alloc((size_t)GG * 4);
    int*    gsize     = (int*)alloc((size_t)NB * 4);
    char*   z1        = ws;                               // ---- zeroed region end
    int*    cursor    = (int*)alloc((size_t)NB * 4);
    int*    row_start = (int*)alloc((size_t)(NN + 1) * 4);
    int*    bsum      = (int*)alloc((size_t)SCAN_NB * 4);
    int*    ssrc      = (int*)alloc((size_t)ETOT * 4);
    int2*   epart     = (int2*)alloc((size_t)NE * 8);
    float*  pooled    = (float*)alloc((size_t)GG * DD * 4);

    hipMemsetAsync(z0, 0, (size_t)(z1 - z0), stream);

    bucket_count<<<PART_NBLK, 256, 0, stream>>>(ei, gsize);
    bucket_scan<<<1, 256, 0, stream>>>(gsize, cursor);
    bucket_partition<<<PART_NBLK, 256, 0, stream>>>(ei, cursor, epart);
    count_deg2<<<(NE / 4 + 255) / 256, 256, 0, stream>>>(epart, deg);
    scan1<<<SCAN_NB, 256, 0, stream>>>(deg, row_start, bsum);
    scan2<<<1, 64, 0, stream>>>(bsum, row_start);
    scan3<<<(NN + 255) / 256, 256, 0, stream>>>(row_start, bsum);
    scatter_final<<<(SF_EDGE_T + NN + 255) / 256, 256, 0, stream>>>(epart, row_start, wcount, ssrc);
    seg_bounds<<<(NN + 255) / 256, 256, 0, stream>>>(batch, gstart, gend);

    const int gemm_grid = (NN + GROWS - 1) / GROWS;
    gemm96<<<gemm_grid, 192, 0, stream>>>(x, Wp, bp, hA, nullptr,
                                          nullptr, nullptr, nullptr, nullptr);

    for (int l = 0; l < NL; l++) {
        gemm96<<<gemm_grid, 192, 0, stream>>>(hA, Wc + (size_t)l * DD * DD, nullptr,
                                              nullptr, hBh,
                                              att_src + (size_t)l * HEADS * DHH,
                                              att_dst + (size_t)l * HEADS * DHH, as_, ad_);
        aggregate<<<NN / 8, 192, 0, stream>>>(hBh, row_start, ssrc, as_, ad_,
                                              bc + (size_t)l * DD,
                                              bn_gamma + (size_t)l * DD, bn_beta + (size_t)l * DD,
                                              bn_mean + (size_t)l * DD, bn_var + (size_t)l * DD,
                                              hA);
    }

    pool_kernel<<<(GG * DD + 255) / 256, 256, 0, stream>>>(hA, gstart, gend, pooled);
    mlp_kernel<<<GG, 128, 0, stream>>>(pooled, W1, b1, W2, b2, W3, b3, out);
}